// Round 3
// baseline (182.044 us; speedup 1.0000x reference)
//
#include <hip/hip_runtime.h>

namespace {
constexpr int S = 1024;
constexpr int H = 512;
constexpr int W = 512;
constexpr int B = 32;
constexpr int OFF = 256; // (S-H)/2 = (S-W)/2

__device__ __forceinline__ int refl(int i) {
    // jnp.mod(i, 2S) with 2S=2048 (pow2): bitmask gives the nonneg residue.
    int m = i & (2 * S - 1);
    return (m < S) ? m : (2 * S - 1 - m);
}

__device__ __forceinline__ bool stripe(int i, int start, int gb, int len, int n, float inv_gb) {
    int d = i - start;
    if (d < 0) return false;
    // exact integer div by runtime gb: float estimate + one-step fixup
    int q = (int)((float)d * inv_gb);
    int r = d - q * gb;
    if (r < 0)        { r += gb; --q; }
    else if (r >= gb) { r -= gb; ++q; }
    return (r < len) && (q < n);
}

__global__ __launch_bounds__(256) void gridmask_kernel(
    const float* __restrict__ images,
    const float* __restrict__ angles,
    const int* __restrict__ gridblock,
    const int* __restrict__ start1,
    const int* __restrict__ start2,
    float* __restrict__ out)
{
    __shared__ unsigned int tabu[512]; // bytes: row stripe [0..1023], col stripe [1024..2047]
    __shared__ float mlds[1024];

    const int tid = threadIdx.x;
    const int blk = blockIdx.x;          // 8192 blocks, 256 per image
    const int b   = blk >> 8;            // block-uniform batch index
    const int pix_base = (blk & 255) << 10;

    // ---- Issue the global image loads FIRST: HBM latency overlaps mask math ----
    const size_t fbase = (size_t)blk * 3072;
    const float4* __restrict__ gin4  = (const float4*)(images + fbase);
    float4* __restrict__       gout4 = (float4*)(out + fbase);
    const float4 p0 = gin4[tid];
    const float4 p1 = gin4[tid + 256];
    const float4 p2 = gin4[tid + 512];

    // ---- Per-image scalars ----
    const float ang = angles[b];
    const int gb = gridblock[b];
    const int s1 = start1[b];
    const int s2 = start2[b];

    const float gbf = (float)gb;
    // match numpy's two-step f32 rounding exactly: no FMA contraction
    int len = (int)(__fadd_rn(__fmul_rn(gbf, 0.6f), 0.5f));
    len = min(max(len, 1), gb - 1);
    const int n = S / gb;
    const float inv_gb = 1.0f / gbf;

    // ---- Phase 0: stripe lookup tables (bitwise-identical to direct eval) ----
    {
        const int i0 = tid << 2;
        unsigned int rw = 0, cw = 0;
#pragma unroll
        for (int k = 0; k < 4; ++k) {
            rw |= ((unsigned int)stripe(i0 + k, s1, gb, len, n, inv_gb)) << (8 * k);
            cw |= ((unsigned int)stripe(i0 + k, s2, gb, len, n, inv_gb)) << (8 * k);
        }
        tabu[tid]       = rw;
        tabu[256 + tid] = cw;
    }
    __syncthreads();

    const unsigned char* __restrict__ rowt = (const unsigned char*)tabu;
    const unsigned char* __restrict__ colt = rowt + 1024;

    float sn, cs;
    sincosf(ang, &sn, &cs);

    // ---- Phase 1: masks for this thread's 4 pixels -> LDS ----
    {
        const int gpix = pix_base + (tid << 2);
        const int y = gpix >> 9;   // row [0,512)
        const int x = gpix & 511;  // col, multiple of 4

        const float c = (float)(S - 1) * 0.5f; // 511.5
        const float Y = (float)(y + OFF) - c;

        float m[4];
#pragma unroll
        for (int i = 0; i < 4; ++i) {
            const float X  = (float)(x + i + OFF) - c;
            const float sx =  cs * X + sn * Y + c;
            const float sy =  cs * Y - sn * X + c;
            const float x0f = floorf(sx);
            const float y0f = floorf(sy);
            const float fx = sx - x0f;
            const float fy = sy - y0f;
            const int x0i = (int)x0f;
            const int y0i = (int)y0f;
            const int x0r = refl(x0i), x1r = refl(x0i + 1);
            const int y0r = refl(y0i), y1r = refl(y0i + 1);
            const int r0 = rowt[y0r], r1 = rowt[y1r];
            const int c0 = colt[x0r], c1 = colt[x1r];
            const float v00 = (r0 | c0) ? 1.0f : 0.0f;
            const float v01 = (r0 | c1) ? 1.0f : 0.0f;
            const float v10 = (r1 | c0) ? 1.0f : 0.0f;
            const float v11 = (r1 | c1) ? 1.0f : 0.0f;
            m[i] = (v00 * (1.0f - fx) + v01 * fx) * (1.0f - fy)
                 + (v10 * (1.0f - fx) + v11 * fx) * fy;
        }
        ((float4*)mlds)[tid] = make_float4(m[0], m[1], m[2], m[3]);
    }
    __syncthreads();

    // ---- Phase 2: fully coalesced multiply sweep ----
#pragma unroll
    for (int j = 0; j < 3; ++j) {
        const int lf = (j << 10) + (tid << 2);   // local float index [0,3072)
        const int q  = lf / 3;                   // pixel of first component
        const int r  = lf - q * 3;
        const float ma = mlds[q];
        const float mb = mlds[q + 1 <= 1023 ? q + 1 : 1023];
        // component c belongs to pixel q + ((r+c) >= 3)
        const float m0 = (r + 0 >= 3) ? mb : ma;
        const float m1 = (r + 1 >= 3) ? mb : ma;
        const float m2 = (r + 2 >= 3) ? mb : ma;
        const float m3 = (r + 3 >= 3) ? mb : ma;
        const float4 p = (j == 0) ? p0 : (j == 1) ? p1 : p2;
        float4 o;
        o.x = p.x * m0;
        o.y = p.y * m1;
        o.z = p.z * m2;
        o.w = p.w * m3;
        gout4[(j << 8) + tid] = o;
    }
}
} // namespace

extern "C" void kernel_launch(void* const* d_in, const int* in_sizes, int n_in,
                              void* d_out, int out_size, void* d_ws, size_t ws_size,
                              hipStream_t stream) {
    const float* images    = (const float*)d_in[0];
    const float* angles    = (const float*)d_in[1];
    const int*   gridblock = (const int*)d_in[2];
    const int*   start1    = (const int*)d_in[3];
    const int*   start2    = (const int*)d_in[4];
    float* outp = (float*)d_out;

    const int blocks = B * H * W / 1024; // 8192 blocks x 256 threads, 4 px/thread
    gridmask_kernel<<<blocks, 256, 0, stream>>>(images, angles, gridblock, start1, start2, outp);
}